// Round 1
// baseline (157.262 us; speedup 1.0000x reference)
//
#include <hip/hip_runtime.h>
#include <math.h>

// HardMoE classifier: B=131072, D=1024, E=6 experts, L=2 labels. All fp32.
// Wave-per-row: 64 lanes × 16 float4-cols each = 1024 cols. Gate weights in
// VGPRs (96), expert weights from global (L2-hot, wave-uniform base). DPP
// reductions (no LDS). f64 fallback when top-2 gate gap < 1e-3 (argmax
// robustness vs numpy reference accumulation order).

static constexpr int Bn = 131072;
static constexpr int Dn = 1024;
static constexpr int En = 6;
static constexpr int ROWS_PER_WAVE = 16;

template <int CTRL>
__device__ __forceinline__ float dpp_row_add(float v) {
  // v += dpp_permuted(v); bound_ctrl=true -> invalid lanes contribute 0.
  return v + __int_as_float(__builtin_amdgcn_update_dpp(
                 0, __float_as_int(v), CTRL, 0xf, 0xf, true));
}

// Full 64-lane sum, result broadcast to all lanes (via readlane 63 -> sgpr).
__device__ __forceinline__ float wave_sum_bcast(float v) {
  v = dpp_row_add<0x111>(v);  // row_shr:1
  v = dpp_row_add<0x112>(v);  // row_shr:2
  v = dpp_row_add<0x114>(v);  // row_shr:4
  v = dpp_row_add<0x118>(v);  // row_shr:8  -> lane15 of each row16 has row sum
  v = dpp_row_add<0x142>(v);  // row_bcast:15
  v = dpp_row_add<0x143>(v);  // row_bcast:31 -> lane 63 has full sum
  return __int_as_float(__builtin_amdgcn_readlane(__float_as_int(v), 63));
}

__device__ __forceinline__ float dot4(float4 a, float4 b) {
  return fmaf(a.x, b.x, fmaf(a.y, b.y, fmaf(a.z, b.z, a.w * b.w)));
}

__global__ __launch_bounds__(256, 3) void hardmoe_kernel(
    const float* __restrict__ cls, const float* __restrict__ gate_w,
    const float* __restrict__ gate_b, const float* __restrict__ expert_w,
    const float* __restrict__ expert_b, float* __restrict__ out) {
  const int lane = threadIdx.x & 63;
  const int wid = (blockIdx.x * blockDim.x + threadIdx.x) >> 6;

  const float4* __restrict__ cls4 = (const float4*)cls;
  const float4* __restrict__ gw4 = (const float4*)gate_w;
  const float4* __restrict__ ew4 = (const float4*)expert_w;

  // Hoist gate weights: gw[e][t] = gate_w[e][t*256 + 4*lane .. +3]
  float4 gw[En][4];
#pragma unroll
  for (int e = 0; e < En; ++e)
#pragma unroll
    for (int t = 0; t < 4; ++t) gw[e][t] = gw4[e * 256 + t * 64 + lane];

  float gb[En];
#pragma unroll
  for (int e = 0; e < En; ++e) gb[e] = gate_b[e];

  const int row0 = wid * ROWS_PER_WAVE;

  float4 c[4], cn[4];
#pragma unroll
  for (int t = 0; t < 4; ++t)
    c[t] = cls4[(size_t)row0 * 256 + t * 64 + lane];

  for (int r = 0; r < ROWS_PER_WAVE; ++r) {
    const int row = row0 + r;
    // Prefetch next row (clamped; last iter re-reads in-bounds, discarded).
    const int nrow = (row + 1 < Bn) ? (row + 1) : row;
#pragma unroll
    for (int t = 0; t < 4; ++t)
      cn[t] = cls4[(size_t)nrow * 256 + t * 64 + lane];

    // ---- gate logits (fp32) ----
    float lg[En];
#pragma unroll
    for (int e = 0; e < En; ++e) {
      float s = 0.f;
#pragma unroll
      for (int t = 0; t < 4; ++t) s += dot4(c[t], gw[e][t]);
      lg[e] = wave_sum_bcast(s) + gb[e];
    }

    // argmax with first-occurrence tiebreak (matches jnp.argmax)
    int best = 0;
    float bv = lg[0], second = -INFINITY;
#pragma unroll
    for (int e = 1; e < En; ++e) {
      if (lg[e] > bv) {
        second = bv; bv = lg[e]; best = e;
      } else if (lg[e] > second) {
        second = lg[e];
      }
    }

    // Rare near-tie: recompute logits in f64 so argmax matches the true
    // (reference) argmax. Wave-uniform branch (lg are readlane-broadcast).
    if (bv - second < 1e-3f) {
      double dbest = -1e300;
      int db_i = 0;
#pragma unroll
      for (int e = 0; e < En; ++e) {
        double s = 0.0;
#pragma unroll
        for (int t = 0; t < 4; ++t) {
          s += (double)c[t].x * (double)gw[e][t].x;
          s += (double)c[t].y * (double)gw[e][t].y;
          s += (double)c[t].z * (double)gw[e][t].z;
          s += (double)c[t].w * (double)gw[e][t].w;
        }
#pragma unroll
        for (int m = 1; m < 64; m <<= 1) s += __shfl_xor(s, m, 64);
        s += (double)gb[e];
        if (s > dbest) { dbest = s; db_i = e; }
      }
      best = db_i;
    }

    // ---- chosen expert's two output dots ----
    const int ebase = best * 512;  // float4 index of expert_w[best][0][0]
    float a0 = 0.f, a1 = 0.f;
#pragma unroll
    for (int t = 0; t < 4; ++t) {
      float4 w0 = ew4[ebase + t * 64 + lane];
      float4 w1 = ew4[ebase + 256 + t * 64 + lane];
      a0 += dot4(c[t], w0);
      a1 += dot4(c[t], w1);
    }
    const float o0 = wave_sum_bcast(a0) + expert_b[best * 2 + 0];
    const float o1 = wave_sum_bcast(a1) + expert_b[best * 2 + 1];
    if (lane == 0) ((float2*)out)[row] = make_float2(o0, o1);

#pragma unroll
    for (int t = 0; t < 4; ++t) c[t] = cn[t];
  }
}

extern "C" void kernel_launch(void* const* d_in, const int* in_sizes, int n_in,
                              void* d_out, int out_size, void* d_ws,
                              size_t ws_size, hipStream_t stream) {
  const float* cls = (const float*)d_in[0];
  const float* gate_w = (const float*)d_in[1];
  const float* gate_b = (const float*)d_in[2];
  const float* expert_w = (const float*)d_in[3];
  const float* expert_b = (const float*)d_in[4];
  float* out = (float*)d_out;

  // 2048 blocks * 4 waves * 16 rows = 131072 rows exactly.
  hipLaunchKernelGGL(hardmoe_kernel, dim3(2048), dim3(256), 0, stream, cls,
                     gate_w, gate_b, expert_w, expert_b, out);
}